// Round 14
// baseline (211.272 us; speedup 1.0000x reference)
//
#include <hip/hip_runtime.h>
#include <stdint.h>

typedef __attribute__((ext_vector_type(8))) short bf16x8;
typedef __attribute__((ext_vector_type(4))) float f32x4;
typedef __attribute__((ext_vector_type(4))) unsigned int u32x4;
typedef unsigned short u16;
typedef unsigned int u32;

#define NLVL 16
#define NNODE 16384
#define DIN 1024
#define DH 256

__device__ __forceinline__ u16 f2bf(float f) {
  u32 u = __builtin_bit_cast(u32, f);
  u += 0x7FFFu + ((u >> 16) & 1u);
  return (u16)(u >> 16);
}
__device__ __forceinline__ float b2f(u16 h) {
  u32 u = ((u32)h) << 16;
  return __builtin_bit_cast(float, u);
}
__device__ __forceinline__ float fsig(float x) {
  return __builtin_amdgcn_rcpf(1.0f + __expf(-x));
}
__device__ __forceinline__ float ftanh(float x) {
  return 1.0f - 2.0f * __builtin_amdgcn_rcpf(__expf(2.0f * x) + 1.0f);
}

__device__ __forceinline__ void async_copy16(const void* g, void* lds) {
  __builtin_amdgcn_global_load_lds((const __attribute__((address_space(1))) void*)g,
                                   (__attribute__((address_space(3))) void*)lds, 16, 0, 0);
}

// L2-bypass (coherence-point) access for intra-kernel cross-block traffic.
__device__ __forceinline__ void gload_x4(u32x4& v, const void* p) {
  asm volatile("global_load_dwordx4 %0, %1, off sc0 sc1" : "=&v"(v) : "v"(p));
}
// SYNCED variant for poll loops: waitcnt INSIDE the asm so the value is valid
// when the asm block returns (plain gload_x4 + immediate read races — R12 bug).
__device__ __forceinline__ u32x4 gload_x4_sync(const void* p) {
  u32x4 v;
  asm volatile("global_load_dwordx4 %0, %1, off sc0 sc1\n\ts_waitcnt vmcnt(0)"
               : "=&v"(v) : "v"(p) : "memory");
  return v;
}
__device__ __forceinline__ void gstore_dw(float* p, float v) {
  asm volatile("global_store_dword %0, %1, off sc0 sc1" :: "v"(p), "v"(v) : "memory");
}
__device__ __forceinline__ void gstore_sh(u16* p, u16 v) {
  u32 w = v;
  asm volatile("global_store_short %0, %1, off sc0 sc1" :: "v"(p), "v"(w) : "memory");
}
__device__ __forceinline__ float aload_f(const float* p) {
  u32 v = __hip_atomic_load((const u32*)p, __ATOMIC_RELAXED, __HIP_MEMORY_SCOPE_AGENT);
  return __builtin_bit_cast(float, v);
}

// ---------------- merged prep: x->bf16 + weight conversion + flag zeroing ----------------
__global__ __launch_bounds__(256) void k_prep(
    const float* __restrict__ x,
    const float* __restrict__ Wioux, const float* __restrict__ Wfx,
    const float* __restrict__ Wiouh, const float* __restrict__ Wfh,
    const float* __restrict__ bioux, const float* __restrict__ bfx,
    const float* __restrict__ biouh, const float* __restrict__ bfh,
    u16* __restrict__ xb, u16* __restrict__ Wxb, u16* __restrict__ Whb,
    float* __restrict__ b1, float* __restrict__ b2, u32* __restrict__ flags) {
  if (blockIdx.x == 8833) {  // zero flags (64KB) + gxflag (4KB) = 69632 B = 4352 uint4
    uint4* p = (uint4*)flags;
#pragma unroll
    for (int i = 0; i < 17; ++i)
      p[threadIdx.x + i * 256] = make_uint4(0u, 0u, 0u, 0u);
    return;
  }
  if (blockIdx.x < 8192) {
    size_t i = (size_t)blockIdx.x * 256 + threadIdx.x;  // one thread = 8 elems
    const float4* p = (const float4*)x + i * 2;
    float4 v0 = p[0], v1 = p[1];
    union { u16 s[8]; uint4 v; } o;
    o.s[0] = f2bf(v0.x); o.s[1] = f2bf(v0.y); o.s[2] = f2bf(v0.z); o.s[3] = f2bf(v0.w);
    o.s[4] = f2bf(v1.x); o.s[5] = f2bf(v1.y); o.s[6] = f2bf(v1.z); o.s[7] = f2bf(v1.w);
    *((uint4*)(xb + i * 8)) = o.v;
    return;
  }
  int t = (blockIdx.x - 8192) * 256 + threadIdx.x;
  if (t < 131072) {  // Wxb [1024][1024] bf16
    int idx = t * 8;
    int row = idx >> 10, col = idx & 1023;
    const float* src = (row < 768) ? (Wioux + (size_t)row * 1024 + col)
                                   : (Wfx + (size_t)(row - 768) * 1024 + col);
    union { u16 s[8]; uint4 v; } o;
#pragma unroll
    for (int j = 0; j < 8; ++j) o.s[j] = f2bf(src[j]);
    *((uint4*)(Wxb + idx)) = o.v;
  } else if (t < 163840) {  // Whb [1024][256] bf16
    int idx = (t - 131072) * 8;
    int row = idx >> 8, col = idx & 255;
    const float* src = (row < 768) ? (Wiouh + (size_t)row * 256 + col)
                                   : (Wfh + (size_t)(row - 768) * 256 + col);
    union { u16 s[8]; uint4 v; } o;
#pragma unroll
    for (int j = 0; j < 8; ++j) o.s[j] = f2bf(src[j]);
    *((uint4*)(Whb + idx)) = o.v;
  } else if (t < 164096) {  // biases
    int idx = (t - 163840) * 8;
#pragma unroll
    for (int j = 0; j < 8; ++j) {
      int i = idx + j;
      if (i < 1024) b1[i] = (i < 768) ? bioux[i] : bfx[i - 768];
      else { int k = i - 1024; b2[k] = (k < 768) ? biouh[k] : bfh[k - 768]; }
    }
  }
}

__device__ __forceinline__ int swz2(int row) { return (row & 3) ^ ((row >> 2) & 3); }

// ---------------- fused persistent kernel ----------------
// 512 blocks x 256 thr, 2 blocks/CU (LDS 2x75264=147KB<160KB).
//  blocks 0..255   : GEMM role — gx level-major from bf16 xb (levels 0-3 after round 0).
//  blocks 256..511 : LEVEL role — dataflow chain (tile, colgrp), old/new child split.
// flags: PER-WAVE granularity — [tile][quad][colgrp] (16 words/tile, 64KB): wave w
// owns nodes w*4..w*4+3 x its 64 cols, acks its OWN stores (vmcnt is per-wave) and
// publishes without any block barrier. Consumer checks child's quad: one dwordx4.
__global__ __launch_bounds__(256) void k_fused(
    const u16* __restrict__ xb, const int* __restrict__ children,
    const u16* __restrict__ Wxb, const u16* __restrict__ Whb,
    const float* __restrict__ b1, const float* __restrict__ b2,
    float* __restrict__ gx, u16* __restrict__ hb, float* __restrict__ cb,
    float* __restrict__ hout, u32* __restrict__ flags, u32* __restrict__ gxflag) {
  __shared__ __align__(16) char smem[75264];
  const int tid = threadIdx.x, w = tid >> 6, l = tid & 63;
  const int bid = blockIdx.x;

  if (bid < 256) {
    // ================= GEMM role (unchanged from R11) =================
    u16* As = (u16*)smem;            // [2][4096] bf16, chunk-swizzled
    u16* Bs = (u16*)(smem + 16384);  // [2][4096]
    const int wm = w >> 1, wn = w & 1;
    for (int r = 0; r < 4; ++r) {
      const int job = bid + r * 256;
      const int level = job >> 6, sub = job & 63;
      const int tM = level * 1024 + (sub >> 3) * 128, tN = (sub & 7) * 128;

      f32x4 acc[4][4];
#pragma unroll
      for (int mt = 0; mt < 4; ++mt)
#pragma unroll
        for (int nt = 0; nt < 4; ++nt) acc[mt][nt] = (f32x4){0.f, 0.f, 0.f, 0.f};

      auto stage = [&](int buf, int t) {
        int k0 = t * 32;
#pragma unroll
        for (int i = 0; i < 2; ++i) {
          int seg = w * 2 + i;
          int row = seg * 16 + (l >> 2);
          int qg = (l & 3) ^ swz2(row);
          async_copy16(xb + (size_t)(tM + row) * 1024 + k0 + qg * 8,
                       &As[buf * 4096 + seg * 512]);
          async_copy16(Wxb + (size_t)(tN + row) * 1024 + k0 + qg * 8,
                       &Bs[buf * 4096 + seg * 512]);
        }
      };
      auto compute = [&](int buf) {
        bf16x8 a[4], b[4];
#pragma unroll
        for (int mt = 0; mt < 4; ++mt) {
          int row = wm * 64 + mt * 16 + (l & 15);
          int cs = (l >> 4) ^ swz2(row);
          a[mt] = *(const bf16x8*)&As[buf * 4096 + row * 32 + cs * 8];
        }
#pragma unroll
        for (int nt = 0; nt < 4; ++nt) {
          int row = wn * 64 + nt * 16 + (l & 15);
          int cs = (l >> 4) ^ swz2(row);
          b[nt] = *(const bf16x8*)&Bs[buf * 4096 + row * 32 + cs * 8];
        }
#pragma unroll
        for (int mt = 0; mt < 4; ++mt)
#pragma unroll
          for (int nt = 0; nt < 4; ++nt)
            acc[mt][nt] = __builtin_amdgcn_mfma_f32_16x16x32_bf16(a[mt], b[nt], acc[mt][nt], 0, 0, 0);
      };

      stage(0, 0);
      __syncthreads();
      int buf = 0;
      for (int t = 0; t < 32; ++t) {
        if (t + 1 < 32) stage(buf ^ 1, t + 1);
        compute(buf);
        __syncthreads();
        buf ^= 1;
      }

#pragma unroll
      for (int mt = 0; mt < 4; ++mt)
#pragma unroll
        for (int nt = 0; nt < 4; ++nt) {
          int col = tN + wn * 64 + nt * 16 + (l & 15);
          float bias = b1[col];
          int rbase = tM + wm * 64 + mt * 16 + (l >> 4) * 4;
#pragma unroll
          for (int rr = 0; rr < 4; ++rr)
            gstore_dw(gx + (size_t)(rbase + rr) * 1024 + col, acc[mt][nt][rr] + bias);
        }
      asm volatile("s_waitcnt vmcnt(0)" ::: "memory");
      __syncthreads();  // all threads' gx stores at coherence point
      if (tid == 0)
        __hip_atomic_fetch_add(gxflag + level, 1u, __ATOMIC_RELAXED, __HIP_MEMORY_SCOPE_AGENT);
      __syncthreads();
    }
    return;
  }

  // ================= LEVEL role =================
  int* chAll = (int*)smem;                 //  4 KB: children for all 16 levels
  u16* hch = (u16*)(smem + 4096);          // 32 KB child h rows, swizzled
  u16* hsum = (u16*)(smem + 36864);        //  8 KB child-sum rows, swizzled
  float* c_lds = (float*)(smem + 45056);   // 17 KB child c slice, padded 68
  float* iouA = (float*)(smem + 62464);    // 12.5 KB activated i,o,u
  const int lb = bid - 256;
  const int ntile = lb & 63;
  const int cg = lb >> 6;
  const int h0 = cg * 64;  // hidden-col range [h0, h0+64)

  // ---- hoist Whb fragments + biases into registers (live across all levels) ----
  bf16x8 w1[3][8];
  int colg_[3]; float b1g_[3];
#pragma unroll
  for (int i = 0; i < 3; ++i) {
    int tt = w * 3 + i;
    int s = tt >> 2, t = tt & 3;
    int colg = s * 256 + h0 + t * 16 + (l & 15);
    colg_[i] = colg;
    b1g_[i] = b2[colg];
    const u16* bp = Whb + (size_t)colg * 256 + (l >> 4) * 8;
#pragma unroll
    for (int ks = 0; ks < 8; ++ks) w1[i][ks] = *(const bf16x8*)(bp + ks * 32);
  }
  bf16x8 w2[4][8];
  float b2g_[4];
#pragma unroll
  for (int nt = 0; nt < 4; ++nt) {
    int hcol = h0 + nt * 16 + (l & 15);
    b2g_[nt] = b2[768 + hcol];
    const u16* bp = Whb + (size_t)(768 + hcol) * 256 + (l >> 4) * 8;
#pragma unroll
    for (int ks = 0; ks < 8; ++ks) w2[nt][ks] = *(const bf16x8*)(bp + ks * 32);
  }

  // ---- preload children for ALL levels of this tile (one-time, cached) ----
#pragma unroll
  for (int k = 0; k < 4; ++k) {
    int id = tid + k * 256;
    chAll[id] = children[(size_t)(id >> 6) * 4096 + ntile * 64 + (id & 63)];
  }
  __syncthreads();

  for (int level = 0; level < NLVL; ++level) {
    const int node0 = level * 1024 + ntile * 16;
    const int* ch = chAll + level * 64;
    const int thr = (level - 1) << 10;  // children >= thr are "new" (level l-1)

    // ---- step 1: poll OLD children flags (already set, ~1 load) + gxflag ----
    if (level > 0 && tid < 64) {
      int child = ch[tid];
      if (child >= 0 && child < thr) {
        const u32* fp = flags + (size_t)(child >> 4) * 16 + ((child >> 2) & 3) * 4;
        for (;;) {
          u32x4 fv = gload_x4_sync(fp);
          if ((fv[0] & fv[1] & fv[2] & fv[3]) != 0u) break;
          __builtin_amdgcn_s_sleep(2);
        }
      }
    }
    if (tid == 0) {
      while (__hip_atomic_load(gxflag + level, __ATOMIC_RELAXED, __HIP_MEMORY_SCOPE_AGENT) < 64u)
        __builtin_amdgcn_s_sleep(2);
    }
    __syncthreads();

    // ---- step 2: issue pass-A gathers (old children only; absent -> zeros) ----
    u32x4 hv[8]; int hc[8];
#pragma unroll
    for (int it = 0; it < 8; ++it) {
      int id = tid + it * 256;
      int row = id >> 5, q = id & 31;
      int child = ch[row]; hc[it] = child;
      hv[it] = (u32x4){0u, 0u, 0u, 0u};
      if (child >= 0 && child < thr)
        gload_x4(hv[it], hb + (size_t)child * 256 + q * 8);
    }
    u32x4 cv[4]; int cc[4];
#pragma unroll
    for (int it = 0; it < 4; ++it) {
      int id = tid + it * 256;
      int row = id >> 4, qq = id & 15;
      int child = ch[row]; cc[it] = child;
      cv[it] = (u32x4){0u, 0u, 0u, 0u};
      if (child >= 0 && child < thr)
        gload_x4(cv[it], cb + (size_t)child * 256 + h0 + qq * 4);
    }

    // ---- step 3: poll NEW children flags (synced loads) ----
    if (level > 0) {
      if (tid < 64) {
        int child = ch[tid];
        if (child >= thr) {  // thr >= 0 here, so implies child >= 0
          const u32* fp = flags + (size_t)(child >> 4) * 16 + ((child >> 2) & 3) * 4;
          for (;;) {
            u32x4 fv = gload_x4_sync(fp);
            if ((fv[0] & fv[1] & fv[2] & fv[3]) != 0u) break;
            __builtin_amdgcn_s_sleep(1);
          }
        }
      }
      __syncthreads();

      // ---- step 4: pass-B gathers (new children) ----
#pragma unroll
      for (int it = 0; it < 8; ++it) {
        int id = tid + it * 256;
        int row = id >> 5, q = id & 31;
        if (hc[it] >= thr)
          gload_x4(hv[it], hb + (size_t)hc[it] * 256 + q * 8);
      }
#pragma unroll
      for (int it = 0; it < 4; ++it) {
        int id = tid + it * 256;
        int row = id >> 4, qq = id & 15;
        if (cc[it] >= thr)
          gload_x4(cv[it], cb + (size_t)cc[it] * 256 + h0 + qq * 4);
      }
    }

    // ---- step 5: drain + LDS writes ----
    asm volatile("s_waitcnt vmcnt(0)"
                 : "+v"(hv[0]), "+v"(hv[1]), "+v"(hv[2]), "+v"(hv[3]),
                   "+v"(hv[4]), "+v"(hv[5]), "+v"(hv[6]), "+v"(hv[7]),
                   "+v"(cv[0]), "+v"(cv[1]), "+v"(cv[2]), "+v"(cv[3]) :: "memory");
    __builtin_amdgcn_sched_barrier(0);
#pragma unroll
    for (int it = 0; it < 8; ++it) {
      int id = tid + it * 256;
      int row = id >> 5, q = id & 31;
      *(u32x4*)&hch[row * 256 + ((q ^ (row & 7)) * 8)] = hv[it];
    }
#pragma unroll
    for (int it = 0; it < 4; ++it) {
      int id = tid + it * 256;
      int row = id >> 4, qq = id & 15;
      *(u32x4*)&c_lds[row * 68 + qq * 4] = cv[it];
    }
    __syncthreads();

    // ---- gx prefetch (agent loads; gxflag verified in step 1) + hsum ----
    float gxv[3][4], fxv[4];
#pragma unroll
    for (int i = 0; i < 3; ++i)
#pragma unroll
      for (int r = 0; r < 4; ++r)
        gxv[i][r] = aload_f(gx + (size_t)(node0 + (l >> 4) * 4 + r) * 1024 + colg_[i]);
    {
      const int node = node0 + w * 4 + (l >> 4);
#pragma unroll
      for (int nt = 0; nt < 4; ++nt)
        fxv[nt] = aload_f(gx + (size_t)node * 1024 + 768 + h0 + nt * 16 + (l & 15));
    }
#pragma unroll
    for (int it = 0; it < 2; ++it) {
      int id = tid + it * 256;
      int row = id >> 5, q = id & 31;
      float s[8] = {0.f, 0.f, 0.f, 0.f, 0.f, 0.f, 0.f, 0.f};
#pragma unroll
      for (int k = 0; k < 4; ++k) {
        int hr = row * 4 + k;
        bf16x8 v = *(const bf16x8*)&hch[hr * 256 + ((q ^ (hr & 7)) * 8)];
#pragma unroll
        for (int j = 0; j < 8; ++j) s[j] += b2f((u16)v[j]);
      }
      union { u16 us[8]; u32x4 v4; } o;
#pragma unroll
      for (int j = 0; j < 8; ++j) o.us[j] = f2bf(s[j]);
      *(u32x4*)&hsum[row * 256 + ((q ^ (row & 7)) * 8)] = o.v4;
    }
    __syncthreads();

    // ---- GEMM1: iou tiles (3 per wave), B-operands from registers ----
    bf16x8 a1[8];
    {
      int arow = l & 15;
#pragma unroll
      for (int ks = 0; ks < 8; ++ks) {
        int chunk = ks * 4 + (l >> 4);
        a1[ks] = *(const bf16x8*)&hsum[arow * 256 + ((chunk ^ (arow & 7)) * 8)];
      }
    }
#pragma unroll
    for (int i = 0; i < 3; ++i) {
      int tt = w * 3 + i;
      int s = tt >> 2, t = tt & 3;
      f32x4 acc = (f32x4){0.f, 0.f, 0.f, 0.f};
#pragma unroll
      for (int ks = 0; ks < 8; ++ks)
        acc = __builtin_amdgcn_mfma_f32_16x16x32_bf16(a1[ks], w1[i][ks], acc, 0, 0, 0);
      float bias = b1g_[i];
#pragma unroll
      for (int r = 0; r < 4; ++r) {
        int nodeL = (l >> 4) * 4 + r;
        float v = acc[r] + gxv[i][r] + bias;
        iouA[nodeL * 196 + s * 64 + t * 16 + (l & 15)] = (s < 2) ? fsig(v) : ftanh(v);
      }
    }
    __syncthreads();

    // ---- GEMM2 (per-child forget gates) + combine + per-wave publish ----
    bf16x8 a2[8];
    {
      int arow = w * 16 + (l & 15);
#pragma unroll
      for (int ks = 0; ks < 8; ++ks) {
        int chunk = ks * 4 + (l >> 4);
        a2[ks] = *(const bf16x8*)&hch[arow * 256 + ((chunk ^ (arow & 7)) * 8)];
      }
    }
    const int nodeL = w * 4 + (l >> 4);
    const int node = node0 + nodeL;
    float hn[4];
#pragma unroll
    for (int nt = 0; nt < 4; ++nt) {
      int hl = nt * 16 + (l & 15);
      int hcol = h0 + hl;
      f32x4 acc = (f32x4){0.f, 0.f, 0.f, 0.f};
#pragma unroll
      for (int ks = 0; ks < 8; ++ks)
        acc = __builtin_amdgcn_mfma_f32_16x16x32_bf16(a2[ks], w2[nt][ks], acc, 0, 0, 0);
      float fx = fxv[nt] + b2g_[nt];
      float fcsum = 0.f;
#pragma unroll
      for (int r = 0; r < 4; ++r)
        fcsum += fsig(fx + acc[r]) * c_lds[(nodeL * 4 + r) * 68 + hl];
      float ig = iouA[nodeL * 196 + hl];
      float og = iouA[nodeL * 196 + 64 + hl];
      float ug = iouA[nodeL * 196 + 128 + hl];
      float cnew = ig * ug + fcsum;
      float hnew = og * ftanh(cnew);
      hn[nt] = hnew;
      if (level + 1 < NLVL) {  // level 15 has no consumers
        gstore_dw(cb + (size_t)node * 256 + hcol, cnew);
        gstore_sh(hb + (size_t)node * 256 + hcol, f2bf(hnew));
      }
    }
    if (level + 1 < NLVL) {
      // per-WAVE ack (vmcnt is a wave counter) + publish; no block barrier.
      asm volatile("s_waitcnt vmcnt(0)" ::: "memory");
      if (l == 0)
        __hip_atomic_store(flags + (size_t)((level << 6) + ntile) * 16 + w * 4 + cg, 1u,
                           __ATOMIC_RELAXED, __HIP_MEMORY_SCOPE_AGENT);
    }
#pragma unroll
    for (int nt = 0; nt < 4; ++nt)
      hout[(size_t)node * 256 + h0 + nt * 16 + (l & 15)] = hn[nt];
  }
}

// ---------------- launch ----------------
extern "C" void kernel_launch(void* const* d_in, const int* in_sizes, int n_in,
                              void* d_out, int out_size, void* d_ws, size_t ws_size,
                              hipStream_t stream) {
  const float* x = (const float*)d_in[0];
  const int* children = (const int*)d_in[1];
  const float* Wioux = (const float*)d_in[2];
  const float* bioux = (const float*)d_in[3];
  const float* Wiouh = (const float*)d_in[4];
  const float* biouh = (const float*)d_in[5];
  const float* Wfx = (const float*)d_in[6];
  const float* bfx = (const float*)d_in[7];
  const float* Wfh = (const float*)d_in[8];
  const float* bfh = (const float*)d_in[9];

  char* ws = (char*)d_ws;
  u16* xb = (u16*)(ws + 0);              // 33,554,432 B
  float* gx = (float*)(ws + 33554432);   // 67,108,864 B
  u16* hb = (u16*)(ws + 100663296);      //  8,388,608 B
  float* cb = (float*)(ws + 109051904);  // 16,777,216 B
  u16* Wxb = (u16*)(ws + 125829120);     //  2,097,152 B
  u16* Whb = (u16*)(ws + 127926272);     //    524,288 B
  float* b1 = (float*)(ws + 128450560);  //      4,096 B
  float* b2 = (float*)(ws + 128454656);  //      4,096 B
  u32* flags = (u32*)(ws + 128458752);   //     65,536 B (1024 tiles x 16 words)
  u32* gxflag = (u32*)(ws + 128524288);  //      4,096 B (16 level counters)
  float* hout = (float*)d_out;

  k_prep<<<8834, 256, 0, stream>>>(x, Wioux, Wfx, Wiouh, Wfh, bioux, bfx, biouh, bfh,
                                   xb, Wxb, Whb, b1, b2, flags);
  k_fused<<<512, 256, 0, stream>>>(xb, children, Wxb, Whb, b1, b2,
                                   gx, hb, cb, hout, flags, gxflag);
}

// Round 15
// 209.313 us; speedup vs baseline: 1.0094x; 1.0094x over previous
//
#include <hip/hip_runtime.h>
#include <stdint.h>

typedef __attribute__((ext_vector_type(8))) short bf16x8;
typedef __attribute__((ext_vector_type(4))) float f32x4;
typedef __attribute__((ext_vector_type(4))) unsigned int u32x4;
typedef unsigned short u16;
typedef unsigned int u32;

#define NLVL 16
#define NNODE 16384
#define DIN 1024
#define DH 256

__device__ __forceinline__ u16 f2bf(float f) {
  u32 u = __builtin_bit_cast(u32, f);
  u += 0x7FFFu + ((u >> 16) & 1u);
  return (u16)(u >> 16);
}
__device__ __forceinline__ float b2f(u16 h) {
  u32 u = ((u32)h) << 16;
  return __builtin_bit_cast(float, u);
}
__device__ __forceinline__ float fsig(float x) {
  return __builtin_amdgcn_rcpf(1.0f + __expf(-x));
}
__device__ __forceinline__ float ftanh(float x) {
  return 1.0f - 2.0f * __builtin_amdgcn_rcpf(__expf(2.0f * x) + 1.0f);
}

__device__ __forceinline__ void async_copy16(const void* g, void* lds) {
  __builtin_amdgcn_global_load_lds((const __attribute__((address_space(1))) void*)g,
                                   (__attribute__((address_space(3))) void*)lds, 16, 0, 0);
}

// L2-bypass (coherence-point) access for intra-kernel cross-block traffic.
__device__ __forceinline__ void gload_x4(u32x4& v, const void* p) {
  asm volatile("global_load_dwordx4 %0, %1, off sc0 sc1" : "=&v"(v) : "v"(p));
}
// SYNCED variant for poll loops: waitcnt INSIDE the asm so the value is valid
// when the asm block returns (plain gload_x4 + immediate read races — R12 bug).
__device__ __forceinline__ u32x4 gload_x4_sync(const void* p) {
  u32x4 v;
  asm volatile("global_load_dwordx4 %0, %1, off sc0 sc1\n\ts_waitcnt vmcnt(0)"
               : "=&v"(v) : "v"(p) : "memory");
  return v;
}
__device__ __forceinline__ void gstore_dw(float* p, float v) {
  asm volatile("global_store_dword %0, %1, off sc0 sc1" :: "v"(p), "v"(v) : "memory");
}
__device__ __forceinline__ void gstore_sh(u16* p, u16 v) {
  u32 w = v;
  asm volatile("global_store_short %0, %1, off sc0 sc1" :: "v"(p), "v"(w) : "memory");
}
__device__ __forceinline__ float aload_f(const float* p) {
  u32 v = __hip_atomic_load((const u32*)p, __ATOMIC_RELAXED, __HIP_MEMORY_SCOPE_AGENT);
  return __builtin_bit_cast(float, v);
}

// ---------------- merged prep: x->bf16 + weight conversion + flag zeroing ----------------
__global__ __launch_bounds__(256) void k_prep(
    const float* __restrict__ x,
    const float* __restrict__ Wioux, const float* __restrict__ Wfx,
    const float* __restrict__ Wiouh, const float* __restrict__ Wfh,
    const float* __restrict__ bioux, const float* __restrict__ bfx,
    const float* __restrict__ biouh, const float* __restrict__ bfh,
    u16* __restrict__ xb, u16* __restrict__ Wxb, u16* __restrict__ Whb,
    float* __restrict__ b1, float* __restrict__ b2, u32* __restrict__ flags) {
  if (blockIdx.x == 8833) {  // zero flags (16KB) + gxf (4KB) = 20480 B = 1280 uint4
    uint4* p = (uint4*)flags;
#pragma unroll
    for (int i = 0; i < 5; ++i)
      p[threadIdx.x + i * 256] = make_uint4(0u, 0u, 0u, 0u);
    return;
  }
  if (blockIdx.x < 8192) {
    size_t i = (size_t)blockIdx.x * 256 + threadIdx.x;  // one thread = 8 elems
    const float4* p = (const float4*)x + i * 2;
    float4 v0 = p[0], v1 = p[1];
    union { u16 s[8]; uint4 v; } o;
    o.s[0] = f2bf(v0.x); o.s[1] = f2bf(v0.y); o.s[2] = f2bf(v0.z); o.s[3] = f2bf(v0.w);
    o.s[4] = f2bf(v1.x); o.s[5] = f2bf(v1.y); o.s[6] = f2bf(v1.z); o.s[7] = f2bf(v1.w);
    *((uint4*)(xb + i * 8)) = o.v;
    return;
  }
  int t = (blockIdx.x - 8192) * 256 + threadIdx.x;
  if (t < 131072) {  // Wxb [1024][1024] bf16
    int idx = t * 8;
    int row = idx >> 10, col = idx & 1023;
    const float* src = (row < 768) ? (Wioux + (size_t)row * 1024 + col)
                                   : (Wfx + (size_t)(row - 768) * 1024 + col);
    union { u16 s[8]; uint4 v; } o;
#pragma unroll
    for (int j = 0; j < 8; ++j) o.s[j] = f2bf(src[j]);
    *((uint4*)(Wxb + idx)) = o.v;
  } else if (t < 163840) {  // Whb [1024][256] bf16
    int idx = (t - 131072) * 8;
    int row = idx >> 8, col = idx & 255;
    const float* src = (row < 768) ? (Wiouh + (size_t)row * 256 + col)
                                   : (Wfh + (size_t)(row - 768) * 256 + col);
    union { u16 s[8]; uint4 v; } o;
#pragma unroll
    for (int j = 0; j < 8; ++j) o.s[j] = f2bf(src[j]);
    *((uint4*)(Whb + idx)) = o.v;
  } else if (t < 164096) {  // biases
    int idx = (t - 163840) * 8;
#pragma unroll
    for (int j = 0; j < 8; ++j) {
      int i = idx + j;
      if (i < 1024) b1[i] = (i < 768) ? bioux[i] : bfx[i - 768];
      else { int k = i - 1024; b2[k] = (k < 768) ? biouh[k] : bfh[k - 768]; }
    }
  }
}

__device__ __forceinline__ int swz2(int row) { return (row & 3) ^ ((row >> 2) & 3); }

// ---------------- fused persistent kernel ----------------
// 512 blocks x 256 thr, 2 blocks/CU (LDS 2x75264=147KB<160KB).
//  blocks 0..255   : GEMM role — gx level-major from bf16 xb; PER-JOB flag publish:
//                    gxf[level][Msub][Nsub&1][Nsub>>1] so consumers gate on their
//                    own 4 jobs, not the whole level (64 jobs).
//  blocks 256..511 : LEVEL role — dataflow chain (tile, colgrp), old/new child split.
// flags: per-tile 4 words (one per colgrp producer), block-level publish (R13).
__global__ __launch_bounds__(256) void k_fused(
    const u16* __restrict__ xb, const int* __restrict__ children,
    const u16* __restrict__ Wxb, const u16* __restrict__ Whb,
    const float* __restrict__ b1, const float* __restrict__ b2,
    float* __restrict__ gx, u16* __restrict__ hb, float* __restrict__ cb,
    float* __restrict__ hout, u32* __restrict__ flags, u32* __restrict__ gxf) {
  __shared__ __align__(16) char smem[75264];
  const int tid = threadIdx.x, w = tid >> 6, l = tid & 63;
  const int bid = blockIdx.x;

  if (bid < 256) {
    // ================= GEMM role =================
    u16* As = (u16*)smem;            // [2][4096] bf16, chunk-swizzled
    u16* Bs = (u16*)(smem + 16384);  // [2][4096]
    const int wm = w >> 1, wn = w & 1;
    for (int r = 0; r < 4; ++r) {
      const int job = bid + r * 256;
      const int level = job >> 6, sub = job & 63;
      const int tM = level * 1024 + (sub >> 3) * 128, tN = (sub & 7) * 128;

      f32x4 acc[4][4];
#pragma unroll
      for (int mt = 0; mt < 4; ++mt)
#pragma unroll
        for (int nt = 0; nt < 4; ++nt) acc[mt][nt] = (f32x4){0.f, 0.f, 0.f, 0.f};

      auto stage = [&](int buf, int t) {
        int k0 = t * 32;
#pragma unroll
        for (int i = 0; i < 2; ++i) {
          int seg = w * 2 + i;
          int row = seg * 16 + (l >> 2);
          int qg = (l & 3) ^ swz2(row);
          async_copy16(xb + (size_t)(tM + row) * 1024 + k0 + qg * 8,
                       &As[buf * 4096 + seg * 512]);
          async_copy16(Wxb + (size_t)(tN + row) * 1024 + k0 + qg * 8,
                       &Bs[buf * 4096 + seg * 512]);
        }
      };
      auto compute = [&](int buf) {
        bf16x8 a[4], b[4];
#pragma unroll
        for (int mt = 0; mt < 4; ++mt) {
          int row = wm * 64 + mt * 16 + (l & 15);
          int cs = (l >> 4) ^ swz2(row);
          a[mt] = *(const bf16x8*)&As[buf * 4096 + row * 32 + cs * 8];
        }
#pragma unroll
        for (int nt = 0; nt < 4; ++nt) {
          int row = wn * 64 + nt * 16 + (l & 15);
          int cs = (l >> 4) ^ swz2(row);
          b[nt] = *(const bf16x8*)&Bs[buf * 4096 + row * 32 + cs * 8];
        }
#pragma unroll
        for (int mt = 0; mt < 4; ++mt)
#pragma unroll
          for (int nt = 0; nt < 4; ++nt)
            acc[mt][nt] = __builtin_amdgcn_mfma_f32_16x16x32_bf16(a[mt], b[nt], acc[mt][nt], 0, 0, 0);
      };

      stage(0, 0);
      __syncthreads();
      int buf = 0;
      for (int t = 0; t < 32; ++t) {
        if (t + 1 < 32) stage(buf ^ 1, t + 1);
        compute(buf);
        __syncthreads();
        buf ^= 1;
      }

#pragma unroll
      for (int mt = 0; mt < 4; ++mt)
#pragma unroll
        for (int nt = 0; nt < 4; ++nt) {
          int col = tN + wn * 64 + nt * 16 + (l & 15);
          float bias = b1[col];
          int rbase = tM + wm * 64 + mt * 16 + (l >> 4) * 4;
#pragma unroll
          for (int rr = 0; rr < 4; ++rr)
            gstore_dw(gx + (size_t)(rbase + rr) * 1024 + col, acc[mt][nt][rr] + bias);
        }
      asm volatile("s_waitcnt vmcnt(0)" ::: "memory");
      __syncthreads();  // all threads' gx stores at coherence point
      if (tid == 0) {
        int Nsub = sub & 7;
        __hip_atomic_store(gxf + ((level * 8 + (sub >> 3)) * 2 + (Nsub & 1)) * 4 + (Nsub >> 1),
                           1u, __ATOMIC_RELAXED, __HIP_MEMORY_SCOPE_AGENT);
      }
    }
    return;
  }

  // ================= LEVEL role =================
  int* chAll = (int*)smem;                 //  4 KB: children for all 16 levels
  u16* hch = (u16*)(smem + 4096);          // 32 KB child h rows, swizzled
  u16* hsum = (u16*)(smem + 36864);        //  8 KB child-sum rows, swizzled
  float* c_lds = (float*)(smem + 45056);   // 17 KB child c slice, padded 68
  float* iouA = (float*)(smem + 62464);    // 12.5 KB activated i,o,u
  const int lb = bid - 256;
  const int ntile = lb & 63;
  const int cg = lb >> 6;
  const int h0 = cg * 64;  // hidden-col range [h0, h0+64)

  // ---- hoist Whb fragments + biases into registers (live across all levels) ----
  bf16x8 w1[3][8];
  int colg_[3]; float b1g_[3];
#pragma unroll
  for (int i = 0; i < 3; ++i) {
    int tt = w * 3 + i;
    int s = tt >> 2, t = tt & 3;
    int colg = s * 256 + h0 + t * 16 + (l & 15);
    colg_[i] = colg;
    b1g_[i] = b2[colg];
    const u16* bp = Whb + (size_t)colg * 256 + (l >> 4) * 8;
#pragma unroll
    for (int ks = 0; ks < 8; ++ks) w1[i][ks] = *(const bf16x8*)(bp + ks * 32);
  }
  bf16x8 w2[4][8];
  float b2g_[4];
#pragma unroll
  for (int nt = 0; nt < 4; ++nt) {
    int hcol = h0 + nt * 16 + (l & 15);
    b2g_[nt] = b2[768 + hcol];
    const u16* bp = Whb + (size_t)(768 + hcol) * 256 + (l >> 4) * 8;
#pragma unroll
    for (int ks = 0; ks < 8; ++ks) w2[nt][ks] = *(const bf16x8*)(bp + ks * 32);
  }

  // ---- preload children for ALL levels of this tile (one-time, cached) ----
#pragma unroll
  for (int k = 0; k < 4; ++k) {
    int id = tid + k * 256;
    chAll[id] = children[(size_t)(id >> 6) * 4096 + ntile * 64 + (id & 63)];
  }
  __syncthreads();

  for (int level = 0; level < NLVL; ++level) {
    const int node0 = level * 1024 + ntile * 16;
    const int* ch = chAll + level * 64;
    const int thr = (level - 1) << 10;  // children >= thr are "new" (level l-1)

    // ---- step 1: poll OLD children flags + THIS BLOCK'S 4 gx-job flags ----
    if (level > 0 && tid < 64) {
      int child = ch[tid];
      if (child >= 0 && child < thr) {
        const u32* fp = flags + (size_t)(child >> 4) * 4;
        for (;;) {
          u32x4 fv = gload_x4_sync(fp);
          if ((fv[0] & fv[1] & fv[2] & fv[3]) != 0u) break;
          __builtin_amdgcn_s_sleep(2);
        }
      }
    }
    if (tid == 0) {
      const u32* gp = gxf + ((level * 8 + (ntile >> 3)) * 2 + (cg >> 1)) * 4;
      for (;;) {
        u32x4 fv = gload_x4_sync(gp);
        if ((fv[0] & fv[1] & fv[2] & fv[3]) != 0u) break;
        __builtin_amdgcn_s_sleep(2);
      }
    }
    __syncthreads();

    // ---- step 2: issue pass-A gathers (old children only; absent -> zeros) ----
    u32x4 hv[8]; int hc[8];
#pragma unroll
    for (int it = 0; it < 8; ++it) {
      int id = tid + it * 256;
      int row = id >> 5, q = id & 31;
      int child = ch[row]; hc[it] = child;
      hv[it] = (u32x4){0u, 0u, 0u, 0u};
      if (child >= 0 && child < thr)
        gload_x4(hv[it], hb + (size_t)child * 256 + q * 8);
    }
    u32x4 cv[4]; int cc[4];
#pragma unroll
    for (int it = 0; it < 4; ++it) {
      int id = tid + it * 256;
      int row = id >> 4, qq = id & 15;
      int child = ch[row]; cc[it] = child;
      cv[it] = (u32x4){0u, 0u, 0u, 0u};
      if (child >= 0 && child < thr)
        gload_x4(cv[it], cb + (size_t)child * 256 + h0 + qq * 4);
    }

    // ---- step 3: poll NEW children flags (synced loads) ----
    if (level > 0) {
      if (tid < 64) {
        int child = ch[tid];
        if (child >= thr) {  // thr >= 0 here, so implies child >= 0
          const u32* fp = flags + (size_t)(child >> 4) * 4;
          for (;;) {
            u32x4 fv = gload_x4_sync(fp);
            if ((fv[0] & fv[1] & fv[2] & fv[3]) != 0u) break;
            __builtin_amdgcn_s_sleep(1);
          }
        }
      }
      __syncthreads();

      // ---- step 4: pass-B gathers (new children) ----
#pragma unroll
      for (int it = 0; it < 8; ++it) {
        int id = tid + it * 256;
        int row = id >> 5, q = id & 31;
        if (hc[it] >= thr)
          gload_x4(hv[it], hb + (size_t)hc[it] * 256 + q * 8);
      }
#pragma unroll
      for (int it = 0; it < 4; ++it) {
        int id = tid + it * 256;
        int row = id >> 4, qq = id & 15;
        if (cc[it] >= thr)
          gload_x4(cv[it], cb + (size_t)cc[it] * 256 + h0 + qq * 4);
      }
    }

    // ---- step 5: drain + LDS writes ----
    asm volatile("s_waitcnt vmcnt(0)"
                 : "+v"(hv[0]), "+v"(hv[1]), "+v"(hv[2]), "+v"(hv[3]),
                   "+v"(hv[4]), "+v"(hv[5]), "+v"(hv[6]), "+v"(hv[7]),
                   "+v"(cv[0]), "+v"(cv[1]), "+v"(cv[2]), "+v"(cv[3]) :: "memory");
    __builtin_amdgcn_sched_barrier(0);
#pragma unroll
    for (int it = 0; it < 8; ++it) {
      int id = tid + it * 256;
      int row = id >> 5, q = id & 31;
      *(u32x4*)&hch[row * 256 + ((q ^ (row & 7)) * 8)] = hv[it];
    }
#pragma unroll
    for (int it = 0; it < 4; ++it) {
      int id = tid + it * 256;
      int row = id >> 4, qq = id & 15;
      *(u32x4*)&c_lds[row * 68 + qq * 4] = cv[it];
    }
    __syncthreads();

    // ---- gx prefetch (agent loads; job flags verified in step 1) + hsum ----
    float gxv[3][4], fxv[4];
#pragma unroll
    for (int i = 0; i < 3; ++i)
#pragma unroll
      for (int r = 0; r < 4; ++r)
        gxv[i][r] = aload_f(gx + (size_t)(node0 + (l >> 4) * 4 + r) * 1024 + colg_[i]);
    {
      const int node = node0 + w * 4 + (l >> 4);
#pragma unroll
      for (int nt = 0; nt < 4; ++nt)
        fxv[nt] = aload_f(gx + (size_t)node * 1024 + 768 + h0 + nt * 16 + (l & 15));
    }
#pragma unroll
    for (int it = 0; it < 2; ++it) {
      int id = tid + it * 256;
      int row = id >> 5, q = id & 31;
      float s[8] = {0.f, 0.f, 0.f, 0.f, 0.f, 0.f, 0.f, 0.f};
#pragma unroll
      for (int k = 0; k < 4; ++k) {
        int hr = row * 4 + k;
        bf16x8 v = *(const bf16x8*)&hch[hr * 256 + ((q ^ (hr & 7)) * 8)];
#pragma unroll
        for (int j = 0; j < 8; ++j) s[j] += b2f((u16)v[j]);
      }
      union { u16 us[8]; u32x4 v4; } o;
#pragma unroll
      for (int j = 0; j < 8; ++j) o.us[j] = f2bf(s[j]);
      *(u32x4*)&hsum[row * 256 + ((q ^ (row & 7)) * 8)] = o.v4;
    }
    __syncthreads();

    // ---- GEMM1: iou tiles (3 per wave), B-operands from registers ----
    bf16x8 a1[8];
    {
      int arow = l & 15;
#pragma unroll
      for (int ks = 0; ks < 8; ++ks) {
        int chunk = ks * 4 + (l >> 4);
        a1[ks] = *(const bf16x8*)&hsum[arow * 256 + ((chunk ^ (arow & 7)) * 8)];
      }
    }
#pragma unroll
    for (int i = 0; i < 3; ++i) {
      int tt = w * 3 + i;
      int s = tt >> 2, t = tt & 3;
      f32x4 acc = (f32x4){0.f, 0.f, 0.f, 0.f};
#pragma unroll
      for (int ks = 0; ks < 8; ++ks)
        acc = __builtin_amdgcn_mfma_f32_16x16x32_bf16(a1[ks], w1[i][ks], acc, 0, 0, 0);
      float bias = b1g_[i];
#pragma unroll
      for (int r = 0; r < 4; ++r) {
        int nodeL = (l >> 4) * 4 + r;
        float v = acc[r] + gxv[i][r] + bias;
        iouA[nodeL * 196 + s * 64 + t * 16 + (l & 15)] = (s < 2) ? fsig(v) : ftanh(v);
      }
    }
    __syncthreads();

    // ---- GEMM2 (per-child forget gates) + combine + publish ----
    bf16x8 a2[8];
    {
      int arow = w * 16 + (l & 15);
#pragma unroll
      for (int ks = 0; ks < 8; ++ks) {
        int chunk = ks * 4 + (l >> 4);
        a2[ks] = *(const bf16x8*)&hch[arow * 256 + ((chunk ^ (arow & 7)) * 8)];
      }
    }
    const int nodeL = w * 4 + (l >> 4);
    const int node = node0 + nodeL;
    float hn[4];
#pragma unroll
    for (int nt = 0; nt < 4; ++nt) {
      int hl = nt * 16 + (l & 15);
      int hcol = h0 + hl;
      f32x4 acc = (f32x4){0.f, 0.f, 0.f, 0.f};
#pragma unroll
      for (int ks = 0; ks < 8; ++ks)
        acc = __builtin_amdgcn_mfma_f32_16x16x32_bf16(a2[ks], w2[nt][ks], acc, 0, 0, 0);
      float fx = fxv[nt] + b2g_[nt];
      float fcsum = 0.f;
#pragma unroll
      for (int r = 0; r < 4; ++r)
        fcsum += fsig(fx + acc[r]) * c_lds[(nodeL * 4 + r) * 68 + hl];
      float ig = iouA[nodeL * 196 + hl];
      float og = iouA[nodeL * 196 + 64 + hl];
      float ug = iouA[nodeL * 196 + 128 + hl];
      float cnew = ig * ug + fcsum;
      float hnew = og * ftanh(cnew);
      hn[nt] = hnew;
      if (level + 1 < NLVL) {  // level 15 has no consumers
        gstore_dw(cb + (size_t)node * 256 + hcol, cnew);
        gstore_sh(hb + (size_t)node * 256 + hcol, f2bf(hnew));
      }
    }
    if (level + 1 < NLVL) {
      asm volatile("s_waitcnt vmcnt(0)" ::: "memory");  // cb/hb stores acked (hout not issued yet)
      __syncthreads();                                   // whole block done
      if (tid == 0)
        __hip_atomic_store(flags + (size_t)((level << 6) + ntile) * 4 + cg, 1u,
                           __ATOMIC_RELAXED, __HIP_MEMORY_SCOPE_AGENT);
    }
    // hout (no consumers) deferred off the publish path
#pragma unroll
    for (int nt = 0; nt < 4; ++nt)
      hout[(size_t)node * 256 + h0 + nt * 16 + (l & 15)] = hn[nt];
  }
}

// ---------------- launch ----------------
extern "C" void kernel_launch(void* const* d_in, const int* in_sizes, int n_in,
                              void* d_out, int out_size, void* d_ws, size_t ws_size,
                              hipStream_t stream) {
  const float* x = (const float*)d_in[0];
  const int* children = (const int*)d_in[1];
  const float* Wioux = (const float*)d_in[2];
  const float* bioux = (const float*)d_in[3];
  const float* Wiouh = (const float*)d_in[4];
  const float* biouh = (const float*)d_in[5];
  const float* Wfx = (const float*)d_in[6];
  const float* bfx = (const float*)d_in[7];
  const float* Wfh = (const float*)d_in[8];
  const float* bfh = (const float*)d_in[9];

  char* ws = (char*)d_ws;
  u16* xb = (u16*)(ws + 0);              // 33,554,432 B
  float* gx = (float*)(ws + 33554432);   // 67,108,864 B
  u16* hb = (u16*)(ws + 100663296);      //  8,388,608 B
  float* cb = (float*)(ws + 109051904);  // 16,777,216 B
  u16* Wxb = (u16*)(ws + 125829120);     //  2,097,152 B
  u16* Whb = (u16*)(ws + 127926272);     //    524,288 B
  float* b1 = (float*)(ws + 128450560);  //      4,096 B
  float* b2 = (float*)(ws + 128454656);  //      4,096 B
  u32* flags = (u32*)(ws + 128458752);   //     16,384 B (1024 tiles x 4 words)
  u32* gxf = (u32*)(ws + 128475136);     //      4,096 B (16x8x2x4 per-job flags)
  float* hout = (float*)d_out;

  k_prep<<<8834, 256, 0, stream>>>(x, Wioux, Wfx, Wiouh, Wfh, bioux, bfx, biouh, bfh,
                                   xb, Wxb, Whb, b1, b2, flags);
  k_fused<<<512, 256, 0, stream>>>(xb, children, Wxb, Whb, b1, b2,
                                   gx, hb, cb, hout, flags, gxf);
}